// Round 1
// baseline (172.819 us; speedup 1.0000x reference)
//
#include <hip/hip_runtime.h>
#include <hip/hip_bf16.h>

#define BT 16384      // B*T rows
#define CDIM 1024
#define HD 64
#define TT 4096

typedef __bf16 bf16x8 __attribute__((ext_vector_type(8)));
typedef float f32x4 __attribute__((ext_vector_type(4)));

__device__ __forceinline__ f32x4 mfma16(bf16x8 a, bf16x8 b, f32x4 c){
  return __builtin_amdgcn_mfma_f32_16x16x32_bf16(a, b, c, 0, 0, 0);
}

// ---------- kernel 1: weights -> bf16 [192][1024]; rows 64..127 (Wq) pre-scaled by 1/8
__global__ __launch_bounds__(256) void wconv_k(const float* __restrict__ Wk,
    const float* __restrict__ Wq, const float* __restrict__ Wv,
    __bf16* __restrict__ Wbf){
  int idx = blockIdx.x*256 + threadIdx.x;   // 49152 threads, 4 elems each
  int e0 = idx*4;
  int n = e0 >> 10;
  int c = e0 & 1023;
  const float* src; float s;
  if (n < 64)      { src = Wk + (size_t)n*CDIM;       s = 1.0f;   }
  else if (n < 128){ src = Wq + (size_t)(n-64)*CDIM;  s = 0.125f; }
  else             { src = Wv + (size_t)(n-128)*CDIM; s = 1.0f;   }
  float4 v = *reinterpret_cast<const float4*>(src + c);
  __bf16* dst = Wbf + e0;
  dst[0]=(__bf16)(v.x*s); dst[1]=(__bf16)(v.y*s);
  dst[2]=(__bf16)(v.z*s); dst[3]=(__bf16)(v.w*s);
}

// ---------- kernel 2: projections. kqv = [k|q|v], each [BT][64] bf16.
// grid 256 blocks x 256 thr; each wave computes 16 rows x all 192 outputs.
__global__ __launch_bounds__(256) void proj_k(const float* __restrict__ x,
    const __bf16* __restrict__ Wbf, __bf16* __restrict__ kqv){
  const int tid  = threadIdx.x;
  const int lane = tid & 63;
  const int w    = tid >> 6;
  const int l15  = lane & 15, g = lane >> 4;
  const long rowbase = (long)blockIdx.x*64 + w*16;

  f32x4 acc[12];
  #pragma unroll
  for (int j=0;j<12;j++) acc[j] = (f32x4)(0.0f);

  const float* xrow = x + (rowbase + l15)*CDIM;
  for (int it=0; it<32; ++it){
    const int kk0 = it*32 + g*8;
    float4 lo = *reinterpret_cast<const float4*>(xrow + kk0);
    float4 hi = *reinterpret_cast<const float4*>(xrow + kk0 + 4);
    bf16x8 a;
    a[0]=(__bf16)lo.x; a[1]=(__bf16)lo.y; a[2]=(__bf16)lo.z; a[3]=(__bf16)lo.w;
    a[4]=(__bf16)hi.x; a[5]=(__bf16)hi.y; a[6]=(__bf16)hi.z; a[7]=(__bf16)hi.w;
    #pragma unroll
    for (int nc=0; nc<12; ++nc){
      bf16x8 b = *reinterpret_cast<const bf16x8*>(Wbf + (size_t)(nc*16 + l15)*CDIM + kk0);
      acc[nc] = mfma16(a, b, acc[nc]);
    }
  }
  #pragma unroll
  for (int nc=0; nc<12; ++nc){
    const int n0  = nc*16 + l15;
    const int mat = n0 >> 6;       // 0=k, 1=q, 2=v
    const int h   = n0 & 63;
    __bf16* dst = kqv + (size_t)mat*BT*HD + h;
    #pragma unroll
    for (int r=0;r<4;r++){
      long row = rowbase + g*4 + r;
      dst[row*HD] = (__bf16)acc[nc][r];
    }
  }
}

// ---------- kernel 3: causal flash attention.
// grid = B * (T/64) = 256 blocks, 256 thr (4 waves x 16 q-rows).
__global__ __launch_bounds__(256) void attn_k(const __bf16* __restrict__ kqv,
                                              float* __restrict__ out){
  const __bf16* k_ws = kqv;
  const __bf16* q_ws = kqv + (size_t)BT*HD;
  const __bf16* v_ws = kqv + (size_t)2*BT*HD;

  __shared__ __bf16 Klds[64][72];     // [key][dim], +8 pad
  __shared__ __bf16 Vt  [64][72];     // [dim][key], +8 pad
  __shared__ __bf16 Plds[4][16][72];  // per-wave P round-trip

  const int tid  = threadIdx.x;
  const int lane = tid & 63;
  const int w    = tid >> 6;
  const int l15  = lane & 15, g = lane >> 4;

  const int b  = blockIdx.x >> 6;
  const int qt = blockIdx.x & 63;
  const long qbase = (long)b*TT + (long)qt*64;   // global row index

  // Q fragments (16 rows x 64 dims), q pre-scaled by 1/8 at projection
  bf16x8 qf0, qf1;
  {
    const __bf16* src = q_ws + (qbase + w*16 + l15)*HD + g*8;
    qf0 = *reinterpret_cast<const bf16x8*>(src);
    qf1 = *reinterpret_cast<const bf16x8*>(src + 32);
  }

  f32x4 o[4];
  #pragma unroll
  for (int ch=0; ch<4; ++ch) o[ch] = (f32x4)(0.0f);
  float m[4], l[4];
  #pragma unroll
  for (int r=0;r<4;r++){ m[r] = -1e30f; l[r] = 0.0f; }

  const int nkv = qt + 1;
  for (int kv=0; kv<nkv; ++kv){
    const long kvbase = (long)b*TT + (long)kv*64;
    __syncthreads();   // previous tile fully consumed before overwrite
    {
      const int key = tid >> 2;          // 0..63
      const int d0  = (tid & 3) * 16;    // 0,16,32,48
      const __bf16* ks = k_ws + (kvbase + key)*HD + d0;
      *reinterpret_cast<bf16x8*>(&Klds[key][d0])   = *reinterpret_cast<const bf16x8*>(ks);
      *reinterpret_cast<bf16x8*>(&Klds[key][d0+8]) = *reinterpret_cast<const bf16x8*>(ks+8);
      const __bf16* vs = v_ws + (kvbase + key)*HD + d0;
      bf16x8 v0 = *reinterpret_cast<const bf16x8*>(vs);
      bf16x8 v1 = *reinterpret_cast<const bf16x8*>(vs+8);
      #pragma unroll
      for (int j=0;j<8;j++) Vt[d0+j][key]   = v0[j];
      #pragma unroll
      for (int j=0;j<8;j++) Vt[d0+8+j][key] = v1[j];
    }
    __syncthreads();

    // S = Q K^T  (16q x 64k), 4 col-chunks of 16 keys
    f32x4 s[4];
    #pragma unroll
    for (int c=0;c<4;c++){
      bf16x8 kb0 = *reinterpret_cast<const bf16x8*>(&Klds[c*16 + l15][g*8]);
      bf16x8 kb1 = *reinterpret_cast<const bf16x8*>(&Klds[c*16 + l15][g*8 + 32]);
      s[c] = mfma16(qf0, kb0, (f32x4)(0.0f));
      s[c] = mfma16(qf1, kb1, s[c]);
    }

    if (kv == qt){   // diagonal tile: causal mask
      #pragma unroll
      for (int c=0;c<4;c++){
        const int key = c*16 + l15;
        #pragma unroll
        for (int r=0;r<4;r++){
          const int qr = w*16 + g*4 + r;
          if (key > qr) s[c][r] = -1e30f;
        }
      }
    }

    // online softmax over this tile's 64 keys
    float alpha[4];
    #pragma unroll
    for (int r=0;r<4;r++){
      float pm = fmaxf(fmaxf(s[0][r], s[1][r]), fmaxf(s[2][r], s[3][r]));
      pm = fmaxf(pm, __shfl_xor(pm, 1));
      pm = fmaxf(pm, __shfl_xor(pm, 2));
      pm = fmaxf(pm, __shfl_xor(pm, 4));
      pm = fmaxf(pm, __shfl_xor(pm, 8));
      const float mn = fmaxf(m[r], pm);
      alpha[r] = __expf(m[r] - mn);
      m[r] = mn;
    }
    #pragma unroll
    for (int c=0;c<4;c++){
      #pragma unroll
      for (int r=0;r<4;r++) s[c][r] = __expf(s[c][r] - m[r]);
    }
    #pragma unroll
    for (int r=0;r<4;r++){
      float rs = s[0][r] + s[1][r] + s[2][r] + s[3][r];
      rs += __shfl_xor(rs, 1);
      rs += __shfl_xor(rs, 2);
      rs += __shfl_xor(rs, 4);
      rs += __shfl_xor(rs, 8);
      l[r] = l[r]*alpha[r] + rs;
    }
    #pragma unroll
    for (int ch=0; ch<4; ++ch){
      #pragma unroll
      for (int r=0;r<4;r++) o[ch][r] *= alpha[r];
    }

    // P -> LDS (C-layout) -> A-frags
    #pragma unroll
    for (int c=0;c<4;c++){
      #pragma unroll
      for (int r=0;r<4;r++) Plds[w][g*4+r][c*16 + l15] = (__bf16)s[c][r];
    }
    bf16x8 pa0 = *reinterpret_cast<const bf16x8*>(&Plds[w][l15][g*8]);
    bf16x8 pa1 = *reinterpret_cast<const bf16x8*>(&Plds[w][l15][g*8 + 32]);

    #pragma unroll
    for (int ch=0; ch<4; ++ch){
      bf16x8 vb0 = *reinterpret_cast<const bf16x8*>(&Vt[ch*16 + l15][g*8]);
      bf16x8 vb1 = *reinterpret_cast<const bf16x8*>(&Vt[ch*16 + l15][g*8 + 32]);
      o[ch] = mfma16(pa0, vb0, o[ch]);
      o[ch] = mfma16(pa1, vb1, o[ch]);
    }
  }

  // epilogue: out[b, q, h] = o / l
  #pragma unroll
  for (int ch=0; ch<4; ++ch){
    #pragma unroll
    for (int r=0;r<4;r++){
      const long qrow = qbase + w*16 + g*4 + r;
      out[qrow*HD + ch*16 + l15] = o[ch][r] / l[r];
    }
  }
}

extern "C" void kernel_launch(void* const* d_in, const int* in_sizes, int n_in,
                              void* d_out, int out_size, void* d_ws, size_t ws_size,
                              hipStream_t stream) {
  const float* x  = (const float*)d_in[0];
  // d_in[1] = mask (tril, implied by causal structure; unused)
  const float* Wk = (const float*)d_in[2];
  const float* Wq = (const float*)d_in[3];
  const float* Wv = (const float*)d_in[4];
  float* out = (float*)d_out;

  char* ws = (char*)d_ws;
  __bf16* Wbf = (__bf16*)ws;                               // 192*1024*2 = 384 KiB
  __bf16* kqv = (__bf16*)(ws + 393216);                    // 3 * 16384*64*2 = 6 MiB

  wconv_k<<<192, 256, 0, stream>>>(Wk, Wq, Wv, Wbf);
  proj_k <<<256, 256, 0, stream>>>(x, Wbf, kqv);
  attn_k <<<256, 256, 0, stream>>>(kqv, out);
}

// Round 2
// 140.427 us; speedup vs baseline: 1.2307x; 1.2307x over previous
//
#include <hip/hip_runtime.h>
#include <hip/hip_bf16.h>

#define BT 16384      // B*T rows
#define CDIM 1024
#define HD 64
#define TT 4096
#define NSPLIT 4

typedef __bf16 bf16x8 __attribute__((ext_vector_type(8)));
typedef float f32x4 __attribute__((ext_vector_type(4)));

__device__ __forceinline__ f32x4 mfma16(bf16x8 a, bf16x8 b, f32x4 c){
  return __builtin_amdgcn_mfma_f32_16x16x32_bf16(a, b, c, 0, 0, 0);
}

// ---------- kernel 1: weights -> bf16 [192][1024]; rows 64..127 (Wq) pre-scaled by 1/8
__global__ __launch_bounds__(256) void wconv_k(const float* __restrict__ Wk,
    const float* __restrict__ Wq, const float* __restrict__ Wv,
    __bf16* __restrict__ Wbf){
  int idx = blockIdx.x*256 + threadIdx.x;   // 49152 threads, 4 elems each
  int e0 = idx*4;
  int n = e0 >> 10;
  int c = e0 & 1023;
  const float* src; float s;
  if (n < 64)      { src = Wk + (size_t)n*CDIM;       s = 1.0f;   }
  else if (n < 128){ src = Wq + (size_t)(n-64)*CDIM;  s = 0.125f; }
  else             { src = Wv + (size_t)(n-128)*CDIM; s = 1.0f;   }
  float4 v = *reinterpret_cast<const float4*>(src + c);
  __bf16* dst = Wbf + e0;
  dst[0]=(__bf16)(v.x*s); dst[1]=(__bf16)(v.y*s);
  dst[2]=(__bf16)(v.z*s); dst[3]=(__bf16)(v.w*s);
}

// ---------- kernel 2: projections. kqv = [k|q|v], each [BT][64] bf16.
__global__ __launch_bounds__(256) void proj_k(const float* __restrict__ x,
    const __bf16* __restrict__ Wbf, __bf16* __restrict__ kqv){
  const int tid  = threadIdx.x;
  const int lane = tid & 63;
  const int w    = tid >> 6;
  const int l15  = lane & 15, g = lane >> 4;
  const long rowbase = (long)blockIdx.x*64 + w*16;

  f32x4 acc[12];
  #pragma unroll
  for (int j=0;j<12;j++) acc[j] = (f32x4)(0.0f);

  const float* xrow = x + (rowbase + l15)*CDIM;
  for (int it=0; it<32; ++it){
    const int kk0 = it*32 + g*8;
    float4 lo = *reinterpret_cast<const float4*>(xrow + kk0);
    float4 hi = *reinterpret_cast<const float4*>(xrow + kk0 + 4);
    bf16x8 a;
    a[0]=(__bf16)lo.x; a[1]=(__bf16)lo.y; a[2]=(__bf16)lo.z; a[3]=(__bf16)lo.w;
    a[4]=(__bf16)hi.x; a[5]=(__bf16)hi.y; a[6]=(__bf16)hi.z; a[7]=(__bf16)hi.w;
    #pragma unroll
    for (int nc=0; nc<12; ++nc){
      bf16x8 b = *reinterpret_cast<const bf16x8*>(Wbf + (size_t)(nc*16 + l15)*CDIM + kk0);
      acc[nc] = mfma16(a, b, acc[nc]);
    }
  }
  #pragma unroll
  for (int nc=0; nc<12; ++nc){
    const int n0  = nc*16 + l15;
    const int mat = n0 >> 6;       // 0=k, 1=q, 2=v
    const int h   = n0 & 63;
    __bf16* dst = kqv + (size_t)mat*BT*HD + h;
    #pragma unroll
    for (int r=0;r<4;r++){
      long row = rowbase + g*4 + r;
      dst[row*HD] = (__bf16)acc[nc][r];
    }
  }
}

// ---------- kernel 3: causal flash attention, KV-split partials.
// grid = B * 64 qtiles * NSPLIT = 1024 blocks, 256 thr (4 waves x 16 q-rows).
__global__ __launch_bounds__(256) void attn_part_k(const __bf16* __restrict__ kqv,
    __bf16* __restrict__ po, float2* __restrict__ pml){
  const __bf16* k_ws = kqv;
  const __bf16* q_ws = kqv + (size_t)BT*HD;
  const __bf16* v_ws = kqv + (size_t)2*BT*HD;

  __shared__ __bf16 Klds[64][72];     // [key][dim], +8 pad
  __shared__ __bf16 Vt  [64][72];     // [dim][key], +8 pad
  __shared__ __bf16 Plds[4][16][72];  // per-wave P round-trip

  const int tid  = threadIdx.x;
  const int lane = tid & 63;
  const int w    = tid >> 6;
  const int l15  = lane & 15, g = lane >> 4;

  const int bi  = blockIdx.x;
  const int b   = bi >> 8;            // 64 qtiles * 4 splits = 256 per batch
  const int rem = bi & 255;
  const int qt  = 63 - (rem >> 2);    // reversed: longest blocks dispatch first
  const int s   = rem & 3;

  const int ntiles = qt + 1;
  const int lo = ( s      * ntiles) / NSPLIT;
  const int hi = ((s + 1) * ntiles) / NSPLIT;
  const int pidx = (b*64 + qt)*NSPLIT + s;

  if (lo == hi){                       // empty split: mark and bail
    if (l15 == 0){
      #pragma unroll
      for (int r=0;r<4;r++)
        pml[pidx*64 + w*16 + g*4 + r] = make_float2(-1e30f, 0.0f);
    }
    return;
  }

  const long qbase = (long)b*TT + (long)qt*64;

  bf16x8 qf0, qf1;
  {
    const __bf16* src = q_ws + (qbase + w*16 + l15)*HD + g*8;
    qf0 = *reinterpret_cast<const bf16x8*>(src);
    qf1 = *reinterpret_cast<const bf16x8*>(src + 32);
  }

  f32x4 o[4];
  #pragma unroll
  for (int ch=0; ch<4; ++ch) o[ch] = (f32x4)(0.0f);
  float m[4], l[4];
  #pragma unroll
  for (int r=0;r<4;r++){ m[r] = -1e30f; l[r] = 0.0f; }

  for (int kv=lo; kv<hi; ++kv){
    const long kvbase = (long)b*TT + (long)kv*64;
    __syncthreads();
    {
      const int key = tid >> 2;
      const int d0  = (tid & 3) * 16;
      const __bf16* ks = k_ws + (kvbase + key)*HD + d0;
      *reinterpret_cast<bf16x8*>(&Klds[key][d0])   = *reinterpret_cast<const bf16x8*>(ks);
      *reinterpret_cast<bf16x8*>(&Klds[key][d0+8]) = *reinterpret_cast<const bf16x8*>(ks+8);
      const __bf16* vs = v_ws + (kvbase + key)*HD + d0;
      bf16x8 v0 = *reinterpret_cast<const bf16x8*>(vs);
      bf16x8 v1 = *reinterpret_cast<const bf16x8*>(vs+8);
      #pragma unroll
      for (int j=0;j<8;j++) Vt[d0+j][key]   = v0[j];
      #pragma unroll
      for (int j=0;j<8;j++) Vt[d0+8+j][key] = v1[j];
    }
    __syncthreads();

    f32x4 sv[4];
    #pragma unroll
    for (int c=0;c<4;c++){
      bf16x8 kb0 = *reinterpret_cast<const bf16x8*>(&Klds[c*16 + l15][g*8]);
      bf16x8 kb1 = *reinterpret_cast<const bf16x8*>(&Klds[c*16 + l15][g*8 + 32]);
      sv[c] = mfma16(qf0, kb0, (f32x4)(0.0f));
      sv[c] = mfma16(qf1, kb1, sv[c]);
    }

    if (kv == qt){   // diagonal tile: causal mask
      #pragma unroll
      for (int c=0;c<4;c++){
        const int key = c*16 + l15;
        #pragma unroll
        for (int r=0;r<4;r++){
          const int qr = w*16 + g*4 + r;
          if (key > qr) sv[c][r] = -1e30f;
        }
      }
    }

    float alpha[4];
    #pragma unroll
    for (int r=0;r<4;r++){
      float pm = fmaxf(fmaxf(sv[0][r], sv[1][r]), fmaxf(sv[2][r], sv[3][r]));
      pm = fmaxf(pm, __shfl_xor(pm, 1));
      pm = fmaxf(pm, __shfl_xor(pm, 2));
      pm = fmaxf(pm, __shfl_xor(pm, 4));
      pm = fmaxf(pm, __shfl_xor(pm, 8));
      const float mn = fmaxf(m[r], pm);
      alpha[r] = __expf(m[r] - mn);
      m[r] = mn;
    }
    #pragma unroll
    for (int c=0;c<4;c++){
      #pragma unroll
      for (int r=0;r<4;r++) sv[c][r] = __expf(sv[c][r] - m[r]);
    }
    #pragma unroll
    for (int r=0;r<4;r++){
      float rs = sv[0][r] + sv[1][r] + sv[2][r] + sv[3][r];
      rs += __shfl_xor(rs, 1);
      rs += __shfl_xor(rs, 2);
      rs += __shfl_xor(rs, 4);
      rs += __shfl_xor(rs, 8);
      l[r] = l[r]*alpha[r] + rs;
    }
    #pragma unroll
    for (int ch=0; ch<4; ++ch){
      #pragma unroll
      for (int r=0;r<4;r++) o[ch][r] *= alpha[r];
    }

    #pragma unroll
    for (int c=0;c<4;c++){
      #pragma unroll
      for (int r=0;r<4;r++) Plds[w][g*4+r][c*16 + l15] = (__bf16)sv[c][r];
    }
    bf16x8 pa0 = *reinterpret_cast<const bf16x8*>(&Plds[w][l15][g*8]);
    bf16x8 pa1 = *reinterpret_cast<const bf16x8*>(&Plds[w][l15][g*8 + 32]);

    #pragma unroll
    for (int ch=0; ch<4; ++ch){
      bf16x8 vb0 = *reinterpret_cast<const bf16x8*>(&Vt[ch*16 + l15][g*8]);
      bf16x8 vb1 = *reinterpret_cast<const bf16x8*>(&Vt[ch*16 + l15][g*8 + 32]);
      o[ch] = mfma16(pa0, vb0, o[ch]);
      o[ch] = mfma16(pa1, vb1, o[ch]);
    }
  }

  // epilogue: store NORMALIZED partial o (bf16) + (m,l) f32
  float rl[4];
  #pragma unroll
  for (int r=0;r<4;r++) rl[r] = (l[r] > 0.0f) ? 1.0f/l[r] : 0.0f;
  __bf16* podst = po + (size_t)pidx*4096;
  #pragma unroll
  for (int ch=0; ch<4; ++ch){
    #pragma unroll
    for (int r=0;r<4;r++)
      podst[(w*16 + g*4 + r)*64 + ch*16 + l15] = (__bf16)(o[ch][r] * rl[r]);
  }
  if (l15 == 0){
    #pragma unroll
    for (int r=0;r<4;r++)
      pml[pidx*64 + w*16 + g*4 + r] = make_float2(m[r], l[r]);
  }
}

// ---------- kernel 4: combine partials. 1M output elems.
__global__ __launch_bounds__(256) void comb_k(const __bf16* __restrict__ po,
    const float2* __restrict__ pml, float* __restrict__ out){
  const int idx = blockIdx.x*256 + threadIdx.x;   // < 1048576
  const int qrow  = idx >> 6;
  const int dim   = idx & 63;
  const int qtg   = qrow >> 6;      // global q-tile 0..255
  const int rowin = qrow & 63;

  float2 ml[NSPLIT];
  float M = -3e30f;
  #pragma unroll
  for (int s=0;s<NSPLIT;s++){
    ml[s] = pml[(qtg*NSPLIT + s)*64 + rowin];
    M = fmaxf(M, ml[s].x);
  }
  float num = 0.0f, den = 0.0f;
  #pragma unroll
  for (int s=0;s<NSPLIT;s++){
    const float wgt = __expf(ml[s].x - M) * ml[s].y;   // W_s * l_s
    den += wgt;
    num += wgt * (float)po[(size_t)(qtg*NSPLIT + s)*4096 + rowin*64 + dim];
  }
  out[idx] = num / den;
}

extern "C" void kernel_launch(void* const* d_in, const int* in_sizes, int n_in,
                              void* d_out, int out_size, void* d_ws, size_t ws_size,
                              hipStream_t stream) {
  const float* x  = (const float*)d_in[0];
  // d_in[1] = mask (tril, implied by causal structure; unused)
  const float* Wk = (const float*)d_in[2];
  const float* Wq = (const float*)d_in[3];
  const float* Wv = (const float*)d_in[4];
  float* out = (float*)d_out;

  char* ws = (char*)d_ws;
  __bf16* Wbf = (__bf16*)ws;                         // 384 KiB (padded to 393216)
  __bf16* kqv = (__bf16*)(ws + 393216);              // 6 MiB
  __bf16* po  = (__bf16*)(ws + 6684672);             // 1024*4096*2 = 8 MiB
  float2* pml = (float2*)(ws + 15073280);            // 1024*64*8 = 512 KiB

  wconv_k    <<<192,  256, 0, stream>>>(Wk, Wq, Wv, Wbf);
  proj_k     <<<256,  256, 0, stream>>>(x, Wbf, kqv);
  attn_part_k<<<1024, 256, 0, stream>>>(kqv, po, pml);
  comb_k     <<<4096, 256, 0, stream>>>(po, pml, out);
}